// Round 7
// baseline (133.527 us; speedup 1.0000x reference)
//
#include <hip/hip_runtime.h>
#include <math.h>

// EnhancedFinancialGAT — analytical collapse (Round 0 proof: all N=2000 node
// rows identical + per-dst softmax sums to 1 (self-loop guarantees denom>=1)
// => each GAT layer is a dense 256->256 relu; edges/attention irrelevant).
//
// Round 13: MFMA batching. R11/R12 showed VALU dot-product structure pays
// ~256 ds_read_b128/CU/layer (every act float4 re-read by 16 lanes) + shfl
// chains — ~9us of LDS port time — on top of the per-CU weight-ingest floor.
// All 64 items share all weights, so batch: 4 blocks x 16 items, each layer
// is [16xK]@[Kx256] on v_mfma_f32_16x16x32_f16. Operand layouts (A: row=l&15,
// k=(l>>4)*8+j; B: col=l&15, same k; C/D: row=(l>>4)*4+reg, col=l&15 [m89])
// make both fragments single contiguous half8 loads: B straight from global
// fp16 weights (compress_w prepass, v6-proven numerics), A from LDS acts.
// Per wave/layer: 8 global half8 + 8 ds_read_b128 + 8 MFMA. fp32 accum.

#define B_ITEMS 64

typedef _Float16 half_t;
typedef _Float16 half8 __attribute__((ext_vector_type(8)));
typedef float f32x4 __attribute__((ext_vector_type(4)));

// ---- fp16 weight layout inside d_ws (element offsets, all mult. of 8) ----
#define OFF_WIN   0        // W_in   [256x64]   16384
#define OFF_GAT   16384    // gat_W  [3x256x256] 196608
#define OFF_FUSE  212992   // W_fuse [256x320]  81920
#define OFF_P1    294912   // W_p1   [128x256]  32768
#define OFF_D1    327680   // W_d1   [128x256]  32768
#define OFF_P2    360448   // W_p2   [64x128]   8192
#define OFF_D2    368640   // W_d2   [64x128]   8192
#define TOT_W     376832   // total halves (753664 B)

// Prepass: fp32 -> fp16, 8 elements/thread. 46 x 1024 threads = TOT_W/8.
extern "C" __global__ __launch_bounds__(1024) void compress_w(
    const float* __restrict__ W_in, const float* __restrict__ gat_W,
    const float* __restrict__ W_fuse, const float* __restrict__ W_p1,
    const float* __restrict__ W_d1, const float* __restrict__ W_p2,
    const float* __restrict__ W_d2, half_t* __restrict__ ws)
{
    const int e = (blockIdx.x * 1024 + threadIdx.x) * 8;
    const float* src;
    int off;
    if      (e < OFF_GAT)  { src = W_in;   off = e; }
    else if (e < OFF_FUSE) { src = gat_W;  off = e - OFF_GAT; }
    else if (e < OFF_P1)   { src = W_fuse; off = e - OFF_FUSE; }
    else if (e < OFF_D1)   { src = W_p1;   off = e - OFF_P1; }
    else if (e < OFF_P2)   { src = W_d1;   off = e - OFF_D1; }
    else if (e < OFF_D2)   { src = W_p2;   off = e - OFF_P2; }
    else                   { src = W_d2;   off = e - OFF_D2; }
    const float4* s4 = reinterpret_cast<const float4*>(src + off);
    float4 a = s4[0], b = s4[1];
    half8 h = { (_Float16)a.x, (_Float16)a.y, (_Float16)a.z, (_Float16)a.w,
                (_Float16)b.x, (_Float16)b.y, (_Float16)b.z, (_Float16)b.w };
    *reinterpret_cast<half8*>(ws + e) = h;
}

#define LDA 328   // halves; 656B row stride -> (164 words % 32) = 4 -> 2-way max

// One MFMA layer tile for this wave: C[16 items x 16 cols] over K = KSTEPS*32.
// Wt = global fp16 W row (this lane's col row), contiguous in k.
// At = LDS act row (this lane's item row), contiguous in k.
template <int KSTEPS>
__device__ __forceinline__ void mfma_tile(const half_t* __restrict__ Wt,
                                          const _Float16* __restrict__ At,
                                          f32x4& c, int kq) {
    const half8* __restrict__ Wp = reinterpret_cast<const half8*>(Wt + kq * 8);
    const _Float16* __restrict__ Ap = At + kq * 8;
#pragma unroll 1
    for (int s = 0; s < KSTEPS; s += 2) {
        half8 b0 = Wp[s * 4];
        half8 a0 = *reinterpret_cast<const half8*>(Ap + s * 32);
        half8 b1 = Wp[s * 4 + 4];
        half8 a1 = *reinterpret_cast<const half8*>(Ap + s * 32 + 32);
        c = __builtin_amdgcn_mfma_f32_16x16x32_f16(a0, b0, c, 0, 0, 0);
        c = __builtin_amdgcn_mfma_f32_16x16x32_f16(a1, b1, c, 0, 0, 0);
    }
}

// C-write: item = kq*4+r (m89: row=(l>>4)*4+reg), col = given; relu(c+bv).
__device__ __forceinline__ void cwrite(f32x4 c, float bv, _Float16* outbase,
                                       int col, int kq) {
#pragma unroll
    for (int r = 0; r < 4; ++r) {
        float v = fmaxf(c[r] + bv, 0.f);
        outbase[(kq * 4 + r) * LDA + col] = (_Float16)v;
    }
}

extern "C" __global__ __launch_bounds__(1024) void fin_gat_v13(
    const float* __restrict__ x,        // [64,64]
    const int* __restrict__ cidx,       // [64]
    const half_t* __restrict__ ws,      // fp16 weights (layout above)
    const float* __restrict__ b_in,
    const float* __restrict__ gat_b,    // [3,256]
    const float* __restrict__ emb,      // [2000,64]
    const float* __restrict__ b_fuse,
    const float* __restrict__ b_p1,
    const float* __restrict__ b_p2,
    const float* __restrict__ W_p3, const float* __restrict__ b_p3,
    const float* __restrict__ b_d1,
    const float* __restrict__ b_d2,
    const float* __restrict__ W_d3, const float* __restrict__ b_d3,
    float* __restrict__ out)            // [128]
{
    __shared__ _Float16 actA[16 * LDA];
    __shared__ _Float16 actB[16 * LDA];
    __shared__ _Float16 xact[16 * 72];

    const int g = blockIdx.x;           // 4 blocks x 16 items
    const int i0 = g * 16;
    const int t = threadIdx.x;
    const int w = t >> 6;               // wave 0..15
    const int lane = t & 63;
    const int r16 = lane & 15;
    const int kq = lane >> 4;

    // ---- prologue: stage x and emb as fp16 (1024 threads = 16 items x 64) ----
    {
        const int item = t >> 6, k = t & 63;
        xact[item * 72 + k] = (_Float16)x[(i0 + item) * 64 + k];
        actB[item * LDA + 256 + k] =
            (_Float16)emb[(size_t)cidx[i0 + item] * 64 + k];   // fuse tail
    }
    __syncthreads();

    // ---- L0: xact[16x64] @ W_in^T -> actA[16x256] ----
    {
        f32x4 c = {0.f, 0.f, 0.f, 0.f};
        mfma_tile<2>(ws + OFF_WIN + (size_t)(w * 16 + r16) * 64,
                     xact + r16 * 72, c, kq);
        cwrite(c, b_in[w * 16 + r16], actA, w * 16 + r16, kq);
    }
    __syncthreads();

    // ---- GAT0: actA -> actB[0:256]  (emb tail at [256:320] untouched) ----
    {
        f32x4 c = {0.f, 0.f, 0.f, 0.f};
        mfma_tile<8>(ws + OFF_GAT + (size_t)(w * 16 + r16) * 256,
                     actA + r16 * LDA, c, kq);
        cwrite(c, gat_b[w * 16 + r16], actB, w * 16 + r16, kq);
    }
    __syncthreads();

    // ---- GAT1: actB -> actA ----
    {
        f32x4 c = {0.f, 0.f, 0.f, 0.f};
        mfma_tile<8>(ws + OFF_GAT + 65536 + (size_t)(w * 16 + r16) * 256,
                     actB + r16 * LDA, c, kq);
        cwrite(c, gat_b[256 + w * 16 + r16], actA, w * 16 + r16, kq);
    }
    __syncthreads();

    // ---- GAT2: actA -> actB[0:256] ----
    {
        f32x4 c = {0.f, 0.f, 0.f, 0.f};
        mfma_tile<8>(ws + OFF_GAT + 131072 + (size_t)(w * 16 + r16) * 256,
                     actA + r16 * LDA, c, kq);
        cwrite(c, gat_b[512 + w * 16 + r16], actB, w * 16 + r16, kq);
    }
    __syncthreads();

    // ---- FUSE: actB[16x320] (gat2 out ++ emb) -> actA ----
    {
        f32x4 c = {0.f, 0.f, 0.f, 0.f};
        mfma_tile<10>(ws + OFF_FUSE + (size_t)(w * 16 + r16) * 320,
                      actB + r16 * LDA, c, kq);
        cwrite(c, b_fuse[w * 16 + r16], actA, w * 16 + r16, kq);
    }
    __syncthreads();

    // ---- P1 (waves 0-7 -> cols 0:128) / D1 (waves 8-15 -> cols 128:256) ----
    {
        f32x4 c = {0.f, 0.f, 0.f, 0.f};
        const half_t* Wt = (w < 8)
            ? ws + OFF_P1 + (size_t)(w * 16 + r16) * 256
            : ws + OFF_D1 + (size_t)((w - 8) * 16 + r16) * 256;
        const float bv = (w < 8) ? b_p1[w * 16 + r16]
                                 : b_d1[(w - 8) * 16 + r16];
        mfma_tile<8>(Wt, actA + r16 * LDA, c, kq);
        cwrite(c, bv, actB, w * 16 + r16, kq);
    }
    __syncthreads();

    // ---- P2 (waves 0-3, K=actB[0:128]) / D2 (waves 4-7, K=actB[128:256]) ----
    if (w < 8) {
        f32x4 c = {0.f, 0.f, 0.f, 0.f};
        const half_t* Wt = (w < 4)
            ? ws + OFF_P2 + (size_t)(w * 16 + r16) * 128
            : ws + OFF_D2 + (size_t)((w - 4) * 16 + r16) * 128;
        const _Float16* At = actB + r16 * LDA + ((w < 4) ? 0 : 128);
        const float bv = (w < 4) ? b_p2[w * 16 + r16]
                                 : b_d2[(w - 4) * 16 + r16];
        mfma_tile<4>(Wt, At, c, kq);
        cwrite(c, bv, actA, w * 16 + r16, kq);   // cols 0:64 p2, 64:128 d2
    }
    __syncthreads();

    // ---- heads: wave w = item w; lanes = k (64) ----
    {
        float v1 = (float)actA[w * LDA + lane] * W_p3[lane];
        float v2 = (float)actA[w * LDA + 64 + lane] * W_d3[lane];
#pragma unroll
        for (int off = 32; off > 0; off >>= 1) {
            v1 += __shfl_down(v1, off, 64);
            v2 += __shfl_down(v2, off, 64);
        }
        if (lane == 0) {
            out[i0 + w] = v1 + b_p3[0];
            const float z = v2 + b_d3[0];
            out[B_ITEMS + i0 + w] = 1.0f / (1.0f + expf(-z));
        }
    }
}

extern "C" void kernel_launch(void* const* d_in, const int* in_sizes, int n_in,
                              void* d_out, int out_size, void* d_ws, size_t ws_size,
                              hipStream_t stream) {
    const float* x      = (const float*)d_in[0];
    const int*   cidx   = (const int*)  d_in[1];
    // d_in[2]=edge_index, d_in[3]=edge_attr -> numerically irrelevant
    const float* W_in   = (const float*)d_in[4];
    const float* b_in   = (const float*)d_in[5];
    const float* gat_W  = (const float*)d_in[6];
    // d_in[7..10] = att params -> irrelevant
    const float* gat_b  = (const float*)d_in[11];
    const float* emb    = (const float*)d_in[12];
    const float* W_fuse = (const float*)d_in[13];
    const float* b_fuse = (const float*)d_in[14];
    const float* W_p1   = (const float*)d_in[15];
    const float* b_p1   = (const float*)d_in[16];
    const float* W_p2   = (const float*)d_in[17];
    const float* b_p2   = (const float*)d_in[18];
    const float* W_p3   = (const float*)d_in[19];
    const float* b_p3   = (const float*)d_in[20];
    const float* W_d1   = (const float*)d_in[21];
    const float* b_d1   = (const float*)d_in[22];
    const float* W_d2   = (const float*)d_in[23];
    const float* b_d2   = (const float*)d_in[24];
    const float* W_d3   = (const float*)d_in[25];
    const float* b_d3   = (const float*)d_in[26];

    half_t* ws = (half_t*)d_ws;   // needs 753664 B of scratch

    compress_w<<<46, 1024, 0, stream>>>(W_in, gat_W, W_fuse, W_p1, W_d1,
                                        W_p2, W_d2, ws);

    fin_gat_v13<<<4, 1024, 0, stream>>>(
        x, cidx, ws, b_in, gat_b, emb, b_fuse,
        b_p1, b_p2, W_p3, b_p3, b_d1, b_d2, W_d3, b_d3,
        (float*)d_out);
}

// Round 8
// 121.940 us; speedup vs baseline: 1.0950x; 1.0950x over previous
//
#include <hip/hip_runtime.h>
#include <math.h>

// EnhancedFinancialGAT — analytical collapse (Round 0 proof: all N=2000 node
// rows identical + per-dst softmax sums to 1 => each GAT layer is a dense
// 256->256 relu; edges/attention irrelevant).
//
// Round 14: MFMA + global_load_lds DMA pipeline. v13 (MFMA, 4 blocks, direct
// global->VGPR weight loads) was latency-doomed: ~1 KB/CU in flight vs the
// 10-64 KB Little's-law requirement at ~700cyc latency. Fix: stream weights
// via __builtin_amdgcn_global_load_lds (zero VGPR cost => a full 64 KB stage
// in flight per CU ~= 90 B/cyc, above the ~60 B/cyc L2 path), double-buffered
// 13 K-split stages with counted vmcnt (never drain), raw asm barriers.
// MFMA consumes each weight byte exactly ONCE from LDS (unlike R10's VALU
// version where 16-lane act re-reads made LDS the bottleneck).
// Bank fix: col-major fp16 rows are a 16-way conflict; XOR-swizzle j^(c&7)
// applied at DMA SOURCE + LDS READ (both sides, rule 21). ws layout and
// compress_w are byte-identical to the proven v6/v13 prepass.

#define B_ITEMS 64

typedef _Float16 half_t;
typedef _Float16 half8 __attribute__((ext_vector_type(8)));
typedef float f32x4 __attribute__((ext_vector_type(4)));

// ---- fp16 weight layout inside d_ws (element offsets) ----
#define OFF_WIN   0        // W_in   [256x64]
#define OFF_GAT   16384    // gat_W  [3x256x256]
#define OFF_FUSE  212992   // W_fuse [256x320]
#define OFF_P1    294912   // W_p1   [128x256]
#define OFF_D1    327680   // W_d1   [128x256]
#define OFF_P2    360448   // W_p2   [64x128]
#define OFF_D2    368640   // W_d2   [64x128]
#define TOT_W     376832

// Prepass: fp32 -> fp16, 8 elements/thread. 46 x 1024 threads = TOT_W/8.
extern "C" __global__ __launch_bounds__(1024) void compress_w(
    const float* __restrict__ W_in, const float* __restrict__ gat_W,
    const float* __restrict__ W_fuse, const float* __restrict__ W_p1,
    const float* __restrict__ W_d1, const float* __restrict__ W_p2,
    const float* __restrict__ W_d2, half_t* __restrict__ ws)
{
    const int e = (blockIdx.x * 1024 + threadIdx.x) * 8;
    const float* src;
    int off;
    if      (e < OFF_GAT)  { src = W_in;   off = e; }
    else if (e < OFF_FUSE) { src = gat_W;  off = e - OFF_GAT; }
    else if (e < OFF_P1)   { src = W_fuse; off = e - OFF_FUSE; }
    else if (e < OFF_D1)   { src = W_p1;   off = e - OFF_P1; }
    else if (e < OFF_P2)   { src = W_d1;   off = e - OFF_D1; }
    else if (e < OFF_D2)   { src = W_p2;   off = e - OFF_P2; }
    else                   { src = W_d2;   off = e - OFF_D2; }
    const float4* s4 = reinterpret_cast<const float4*>(src + off);
    float4 a = s4[0], b = s4[1];
    half8 h = { (_Float16)a.x, (_Float16)a.y, (_Float16)a.z, (_Float16)a.w,
                (_Float16)b.x, (_Float16)b.y, (_Float16)b.z, (_Float16)b.w };
    *reinterpret_cast<half8*>(ws + e) = h;
}

#define LDA 328   // act row stride in halves (656 B -> conflict-benign)

#define WAITV(N)  asm volatile("s_waitcnt vmcnt(" #N ")" ::: "memory")
#define LGKM0()   asm volatile("s_waitcnt lgkmcnt(0)" ::: "memory")
#define BARRIER() asm volatile("s_barrier" ::: "memory")

// async 16B global->LDS (per-lane source, linear LDS dest = base + lane*16)
__device__ __forceinline__ void g2l16(const half_t* g, half_t* l) {
    __builtin_amdgcn_global_load_lds(
        (const __attribute__((address_space(1))) void*)g,
        (__attribute__((address_space(3))) void*)l, 16, 0, 0);
}

// DMA one K-split stage into lbuf. Stage = VC virtual cols x (NCH 16B chunks).
// Dest chunk n holds source chunk ((n&(NCH-1)) ^ (c&7)) of col c = n>>LNCH
// (XOR bank swizzle baked via the per-lane SOURCE address; LDS stays linear).
template <int LNCH, int NCHUNK, int ROWH, int KOFFC>
__device__ __forceinline__ void dma_stage(const half_t* __restrict__ base,
                                          half_t* lbuf, int t) {
#pragma unroll
    for (int i = 0; i < NCHUNK / 1024; ++i) {
        const int n = i * 1024 + t;
        const int c = n >> LNCH;
        const int j = (n & ((1 << LNCH) - 1)) ^ (c & 7);
        g2l16(base + (size_t)c * ROWH + (KOFFC + j) * 8, lbuf + (size_t)n * 8);
    }
}

// Split variant: vcols [0,CS) from baseA, [CS,VC) from baseB.
template <int LNCH, int NCHUNK, int ROWH, int KOFFC, int CS>
__device__ __forceinline__ void dma_split(const half_t* __restrict__ baseA,
                                          const half_t* __restrict__ baseB,
                                          half_t* lbuf, int t) {
#pragma unroll
    for (int i = 0; i < NCHUNK / 1024; ++i) {
        const int n = i * 1024 + t;
        const int c = n >> LNCH;
        const int j = (n & ((1 << LNCH) - 1)) ^ (c & 7);
        const half_t* base = (c < CS) ? baseA + (size_t)c * ROWH
                                      : baseB + (size_t)(c - CS) * ROWH;
        g2l16(base + (KOFFC + j) * 8, lbuf + (size_t)n * 8);
    }
}

// Consume one stage: STEPS k-slices of 32. B-frag (lane: col=cloc, k-slice s,
// kq quarter) read with the same XOR; A-frag from acts LDS.
// MFMA layouts per m89: A row=l&15 (item), B col=l&15, k=(l>>4)*8+j.
template <int LNCH, int STEPS>
__device__ __forceinline__ void consume(const half_t* __restrict__ lbuf,
                                        const _Float16* __restrict__ Arow,
                                        int cloc, int kq, f32x4& acc) {
#pragma unroll
    for (int s = 0; s < STEPS; ++s) {
        const int j = (s * 4 + kq) ^ (cloc & 7);
        half8 bf = *reinterpret_cast<const half8*>(
            lbuf + (size_t)((cloc << LNCH) + j) * 8);
        half8 af = *reinterpret_cast<const half8*>(Arow + s * 32 + kq * 8);
        acc = __builtin_amdgcn_mfma_f32_16x16x32_f16(af, bf, acc, 0, 0, 0);
    }
}

extern "C" __global__ __launch_bounds__(1024) void fin_gat_v14(
    const float* __restrict__ x,        // [64,64]
    const int* __restrict__ cidx,       // [64]
    const half_t* __restrict__ ws,      // fp16 weights (layout above)
    const float* __restrict__ b_in,
    const float* __restrict__ gat_b,    // [3,256]
    const float* __restrict__ emb,      // [2000,64]
    const float* __restrict__ b_fuse,
    const float* __restrict__ b_p1,
    const float* __restrict__ b_p2,
    const float* __restrict__ W_p3, const float* __restrict__ b_p3,
    const float* __restrict__ b_d1,
    const float* __restrict__ b_d2,
    const float* __restrict__ W_d3, const float* __restrict__ b_d3,
    float* __restrict__ out)            // [128]
{
    __shared__ half_t wbuf[2][32768];       // 2 x 64 KB weight stages
    __shared__ _Float16 actA[16 * LDA];
    __shared__ _Float16 actB[16 * LDA];
    __shared__ _Float16 xact[16 * 72];

    const int g = blockIdx.x;               // 4 blocks x 16 items
    const int i0 = g * 16;
    const int t = threadIdx.x;
    const int w = t >> 6;                   // wave 0..15
    const int lane = t & 63;
    const int r16 = lane & 15;
    const int kq = lane >> 4;
    const int col = w * 16 + r16;           // this lane's output col (0..255)

    // ---- prologue: acts + ALL biases/head weights into regs, then sync ----
    {
        const int item = t >> 6, k = t & 63;
        xact[item * 72 + k] = (_Float16)x[(i0 + item) * 64 + k];
        actB[item * LDA + 256 + k] =
            (_Float16)emb[(size_t)cidx[i0 + item] * 64 + k];  // fuse tail
    }
    const float bv0 = b_in[col];
    const float bg0 = gat_b[col], bg1 = gat_b[256 + col], bg2 = gat_b[512 + col];
    const float bfu = b_fuse[col];
    const float bh1 = (w < 8) ? b_p1[col] : b_d1[col - 128];
    const float bh2 = (w < 8) ? ((w < 4) ? b_p2[col] : b_d2[col - 64]) : 0.f;
    const float w3p = W_p3[lane], w3d = W_d3[lane];
    const float b3p = b_p3[0], b3d = b_d3[0];
    __syncthreads();                         // drains ALL prologue vmem+lds

    f32x4 acc = {0.f, 0.f, 0.f, 0.f};

    // ---- S0 issue: W_in [256c x 64h] = 2048 chunks ----
    dma_stage<3, 2048, 64, 0>(ws + OFF_WIN, wbuf[0], t);

    // ==== step 0: L0 (Win) -> actA ====
    dma_stage<4, 4096, 256, 0>(ws + OFF_GAT, wbuf[1], t);            // S1 G0a
    WAITV(4); BARRIER();
    consume<3, 2>(wbuf[0], xact + r16 * 72, col, kq, acc);
#pragma unroll
    for (int r = 0; r < 4; ++r)
        actA[(kq * 4 + r) * LDA + col] = (_Float16)fmaxf(acc[r] + bv0, 0.f);
    LGKM0(); BARRIER();

    // ==== step 1: G0a (k 0..127) ====
    dma_stage<4, 4096, 256, 16>(ws + OFF_GAT, wbuf[0], t);           // S2 G0b
    WAITV(4); BARRIER();
    acc = f32x4{0.f, 0.f, 0.f, 0.f};
    consume<4, 4>(wbuf[1], actA + r16 * LDA, col, kq, acc);
    LGKM0(); BARRIER();

    // ==== step 2: G0b (k 128..255) -> actB ====
    dma_stage<4, 4096, 256, 0>(ws + OFF_GAT + 65536, wbuf[1], t);    // S3 G1a
    WAITV(4); BARRIER();
    consume<4, 4>(wbuf[0], actA + r16 * LDA + 128, col, kq, acc);
#pragma unroll
    for (int r = 0; r < 4; ++r)
        actB[(kq * 4 + r) * LDA + col] = (_Float16)fmaxf(acc[r] + bg0, 0.f);
    LGKM0(); BARRIER();

    // ==== step 3: G1a ====
    dma_stage<4, 4096, 256, 16>(ws + OFF_GAT + 65536, wbuf[0], t);   // S4 G1b
    WAITV(4); BARRIER();
    acc = f32x4{0.f, 0.f, 0.f, 0.f};
    consume<4, 4>(wbuf[1], actB + r16 * LDA, col, kq, acc);
    LGKM0(); BARRIER();

    // ==== step 4: G1b -> actA ====
    dma_stage<4, 4096, 256, 0>(ws + OFF_GAT + 131072, wbuf[1], t);   // S5 G2a
    WAITV(4); BARRIER();
    consume<4, 4>(wbuf[0], actB + r16 * LDA + 128, col, kq, acc);
#pragma unroll
    for (int r = 0; r < 4; ++r)
        actA[(kq * 4 + r) * LDA + col] = (_Float16)fmaxf(acc[r] + bg1, 0.f);
    LGKM0(); BARRIER();

    // ==== step 5: G2a ====
    dma_stage<4, 4096, 256, 16>(ws + OFF_GAT + 131072, wbuf[0], t);  // S6 G2b
    WAITV(4); BARRIER();
    acc = f32x4{0.f, 0.f, 0.f, 0.f};
    consume<4, 4>(wbuf[1], actA + r16 * LDA, col, kq, acc);
    LGKM0(); BARRIER();

    // ==== step 6: G2b -> actB ====
    dma_stage<4, 4096, 320, 0>(ws + OFF_FUSE, wbuf[1], t);           // S7 FUa
    WAITV(4); BARRIER();
    consume<4, 4>(wbuf[0], actA + r16 * LDA + 128, col, kq, acc);
#pragma unroll
    for (int r = 0; r < 4; ++r)
        actB[(kq * 4 + r) * LDA + col] = (_Float16)fmaxf(acc[r] + bg2, 0.f);
    LGKM0(); BARRIER();

    // ==== step 7: FUa (k 0..127) ====
    dma_stage<4, 4096, 320, 16>(ws + OFF_FUSE, wbuf[0], t);          // S8 FUb
    WAITV(4); BARRIER();
    acc = f32x4{0.f, 0.f, 0.f, 0.f};
    consume<4, 4>(wbuf[1], actB + r16 * LDA, col, kq, acc);
    LGKM0(); BARRIER();

    // ==== step 8: FUb (k 128..255) ====
    dma_stage<3, 2048, 320, 32>(ws + OFF_FUSE, wbuf[1], t);          // S9 FUc
    WAITV(2); BARRIER();
    consume<4, 4>(wbuf[0], actB + r16 * LDA + 128, col, kq, acc);
    LGKM0(); BARRIER();

    // ==== step 9: FUc (k 256..319 = emb tail) -> actA ====
    dma_split<4, 4096, 256, 0, 128>(ws + OFF_P1, ws + OFF_D1,
                                    wbuf[0], t);                     // S10 PD1a
    WAITV(4); BARRIER();
    consume<3, 2>(wbuf[1], actB + r16 * LDA + 256, col, kq, acc);
#pragma unroll
    for (int r = 0; r < 4; ++r)
        actA[(kq * 4 + r) * LDA + col] = (_Float16)fmaxf(acc[r] + bfu, 0.f);
    LGKM0(); BARRIER();

    // ==== step 10: PD1a ====
    dma_split<4, 4096, 256, 16, 128>(ws + OFF_P1, ws + OFF_D1,
                                     wbuf[1], t);                    // S11 PD1b
    WAITV(4); BARRIER();
    acc = f32x4{0.f, 0.f, 0.f, 0.f};
    consume<4, 4>(wbuf[0], actA + r16 * LDA, col, kq, acc);
    LGKM0(); BARRIER();

    // ==== step 11: PD1b -> actB ====
    dma_split<4, 2048, 128, 0, 64>(ws + OFF_P2, ws + OFF_D2,
                                   wbuf[0], t);                      // S12 PD2
    WAITV(2); BARRIER();
    consume<4, 4>(wbuf[1], actA + r16 * LDA + 128, col, kq, acc);
#pragma unroll
    for (int r = 0; r < 4; ++r)
        actB[(kq * 4 + r) * LDA + col] = (_Float16)fmaxf(acc[r] + bh1, 0.f);
    LGKM0(); BARRIER();

    // ==== step 12: PD2 -> actA cols 0:128 (waves 0-7 only) ====
    WAITV(0); BARRIER();
    if (w < 8) {
        acc = f32x4{0.f, 0.f, 0.f, 0.f};
        const int koff = (w < 4) ? 0 : 128;   // p2 reads p1-out, d2 reads d1-out
        consume<4, 4>(wbuf[0], actB + r16 * LDA + koff, col, kq, acc);
#pragma unroll
        for (int r = 0; r < 4; ++r)
            actA[(kq * 4 + r) * LDA + col] = (_Float16)fmaxf(acc[r] + bh2, 0.f);
    }
    LGKM0(); BARRIER();

    // ---- heads: wave w = item w; lanes = 64 k ----
    {
        float v1 = (float)actA[w * LDA + lane] * w3p;
        float v2 = (float)actA[w * LDA + 64 + lane] * w3d;
#pragma unroll
        for (int off = 32; off > 0; off >>= 1) {
            v1 += __shfl_down(v1, off, 64);
            v2 += __shfl_down(v2, off, 64);
        }
        if (lane == 0) {
            out[i0 + w] = v1 + b3p;
            const float z = v2 + b3d;
            out[B_ITEMS + i0 + w] = 1.0f / (1.0f + expf(-z));
        }
    }
}

extern "C" void kernel_launch(void* const* d_in, const int* in_sizes, int n_in,
                              void* d_out, int out_size, void* d_ws, size_t ws_size,
                              hipStream_t stream) {
    const float* x      = (const float*)d_in[0];
    const int*   cidx   = (const int*)  d_in[1];
    // d_in[2]=edge_index, d_in[3]=edge_attr -> numerically irrelevant
    const float* W_in   = (const float*)d_in[4];
    const float* b_in   = (const float*)d_in[5];
    const float* gat_W  = (const float*)d_in[6];
    // d_in[7..10] = att params -> irrelevant
    const float* gat_b  = (const float*)d_in[11];
    const float* emb    = (const float*)d_in[12];
    const float* W_fuse = (const float*)d_in[13];
    const float* b_fuse = (const float*)d_in[14];
    const float* W_p1   = (const float*)d_in[15];
    const float* b_p1   = (const float*)d_in[16];
    const float* W_p2   = (const float*)d_in[17];
    const float* b_p2   = (const float*)d_in[18];
    const float* W_p3   = (const float*)d_in[19];
    const float* b_p3   = (const float*)d_in[20];
    const float* W_d1   = (const float*)d_in[21];
    const float* b_d1   = (const float*)d_in[22];
    const float* W_d2   = (const float*)d_in[23];
    const float* b_d2   = (const float*)d_in[24];
    const float* W_d3   = (const float*)d_in[25];
    const float* b_d3   = (const float*)d_in[26];

    half_t* ws = (half_t*)d_ws;   // needs 753664 B of scratch

    compress_w<<<46, 1024, 0, stream>>>(W_in, gat_W, W_fuse, W_p1, W_d1,
                                        W_p2, W_d2, ws);

    fin_gat_v14<<<4, 1024, 0, stream>>>(
        x, cidx, ws, b_in, gat_b, emb, b_fuse,
        b_p1, b_p2, W_p3, b_p3, b_d1, b_d2, W_d3, b_d3,
        (float*)d_out);
}